// Round 19
// baseline (619.087 us; speedup 1.0000x reference)
//
#include <hip/hip_runtime.h>
#include <hip/hip_bf16.h>
#include <math.h>

// ---------------------------------------------------------------------------
// GCN predictor: 2x GCNConv(relu) -> mean pool + global feats -> MLP head
// N=100K nodes, E=3.2M directed edges, H=64.
// R19: l2fuse re-laid-out as 16-lanes-per-node x 4 fp8-features-per-lane:
// each gather step is 1 dword load (4 features) + 1 ssrc load per lane
// (wave: 2 load-inst for 4 rows vs R17's 8), divergent per-group loop bounds
// (exec mask, no clamps/dummy loads), matmul 64 bperm + 256 fmac (was 256
// bperm). ~2x fewer wave-instructions in the issue-bound kernel.
// R18 lesson: keep broadcasts on the LDS pipe (__shfl/ds_bpermute), NOT
// readlane (VALU) -- the pipes co-issue.
// Lessons held: no hot-address device atomics; no global atomics on edge
// path; 4-node/low-VGPR tasks; fp8 h1s (64B rows); no degree sort.
// ---------------------------------------------------------------------------

#define BUCKET 256
#define MAXB   512    // max buckets (needs n <= 131072)
#define NCHV   2048   // edge chunks
#define Q      8      // csr record slices per bucket
#define RCOPY  32     // spread copies for the mean-pool accumulator

// per-chunk bucket histogram: gcounts[chunk*NBK + bucket]
__global__ void k_hist(const int* __restrict__ dst, int E, int chunk,
                       int* __restrict__ gcounts, int NBK) {
    __shared__ int lcnt[MAXB];
    for (int i = threadIdx.x; i < NBK; i += blockDim.x) lcnt[i] = 0;
    __syncthreads();
    int e0 = blockIdx.x * chunk;
    int e1 = min(e0 + chunk, E);
    for (int e = e0 + threadIdx.x; e < e1; e += blockDim.x)
        atomicAdd(&lcnt[dst[e] >> 8], 1);
    __syncthreads();
    for (int b = threadIdx.x; b < NBK; b += blockDim.x)
        gcounts[blockIdx.x * NBK + b] = lcnt[b];
}

// per-bucket totals: btot[b] = sum_c gcounts[c*NBK+b]
__global__ void k_colsum(const int* __restrict__ gcounts, int* __restrict__ btot,
                         int NBK, int NCH) {
    __shared__ int lds[256];
    int b = blockIdx.x, t = threadIdx.x;
    int s = 0;
    for (int c = t; c < NCH; c += 256) s += gcounts[c * NBK + b];
    lds[t] = s;
    __syncthreads();
    for (int off = 128; off; off >>= 1) {
        if (t < off) lds[t] += lds[t + off];
        __syncthreads();
    }
    if (t == 0) btot[b] = lds[0];
}

// single block: bucket_base = exclusive scan of btot; zero-init red copies
__global__ void k_scanA(const int* __restrict__ btot, int* __restrict__ bucket_base,
                        float* __restrict__ red, int NBK) {
    __shared__ int lds[MAXB];
    int t = threadIdx.x;
    for (int i = t; i < RCOPY * 64; i += MAXB) red[i] = 0.f;
    int v = (t < NBK) ? btot[t] : 0;
    lds[t] = v;
    __syncthreads();
    for (int off = 1; off < MAXB; off <<= 1) {
        int add = (t >= off) ? lds[t - off] : 0;
        __syncthreads();
        lds[t] += add;
        __syncthreads();
    }
    if (t < NBK) bucket_base[t] = lds[t] - v;
    if (t == NBK - 1) bucket_base[NBK] = lds[t];
}

// per bucket: exclusive scan of gcounts[c*NBK+b] over c, in place
__global__ void k_scanB(int* __restrict__ gcounts, const int* __restrict__ bucket_base,
                        int NBK, int NCH) {
    __shared__ int lds[512];
    int b = blockIdx.x, t = threadIdx.x;
    int carry = bucket_base[b];
    for (int base = 0; base < NCH; base += 512) {
        int c = base + t;
        int v = (c < NCH) ? gcounts[c * NBK + b] : 0;
        lds[t] = v;
        __syncthreads();
        for (int off = 1; off < 512; off <<= 1) {
            int add = (t >= off) ? lds[t - off] : 0;
            __syncthreads();
            lds[t] += add;
            __syncthreads();
        }
        if (c < NCH) gcounts[c * NBK + b] = carry + lds[t] - v;
        int tot = lds[511];
        __syncthreads();
        carry += tot;
    }
}

// scatter packed records (local_d<<17 | src) into bucket-grouped order
__global__ void k_bucketize(const int* __restrict__ src, const int* __restrict__ dst,
                            int E, int chunk, const int* __restrict__ gcounts,
                            int* __restrict__ records, int NBK) {
    __shared__ int lcur[MAXB];
    for (int b = threadIdx.x; b < NBK; b += blockDim.x)
        lcur[b] = gcounts[blockIdx.x * NBK + b];
    __syncthreads();
    int e0 = blockIdx.x * chunk;
    int e1 = min(e0 + chunk, E);
    for (int e = e0 + threadIdx.x; e < e1; e += blockDim.x) {
        int d = dst[e];
        int b = d >> 8;
        int rec = ((d & 255) << 17) | src[e];
        int slot = atomicAdd(&lcur[b], 1);
        records[slot] = rec;
    }
}

// csrA: per-(bucket, slice) histogram of local nodes -> qhist
__global__ void k_csrA(const int* __restrict__ records, const int* __restrict__ bucket_base,
                       int* __restrict__ qhist) {
    __shared__ int cnt[BUCKET];
    int t = threadIdx.x, b = blockIdx.x, q = blockIdx.y;
    if (t < BUCKET) cnt[t] = 0;
    __syncthreads();
    int j0 = bucket_base[b], j1 = bucket_base[b + 1];
    int qlen = (j1 - j0 + Q - 1) / Q;
    int qs = j0 + q * qlen;
    int qe = min(qs + qlen, j1);
    for (int j = qs + t; j < qe; j += blockDim.x)
        atomicAdd(&cnt[records[j] >> 17], 1);
    __syncthreads();
    if (t < BUCKET) qhist[(b * Q + q) * BUCKET + t] = cnt[t];
}

// csrB: per-bucket scan of summed slice histograms -> pos/rowend/dinv/xs,
// per-slice cursor bases qbase, per-block gf partials (no hot atomics)
__global__ void k_csrB(const int* __restrict__ qhist, const int* __restrict__ bucket_base,
                       const float* __restrict__ x,
                       int* __restrict__ qbase, int* __restrict__ pos,
                       int* __restrict__ rowend, float* __restrict__ dinv,
                       float* __restrict__ xs, float* __restrict__ gfpart, int n) {
    __shared__ int lds[BUCKET];
    __shared__ float gf6[8];
    int t = threadIdx.x, b = blockIdx.x;
    if (t < 8) gf6[t] = 0.f;
    int h[Q];
    int c = 0;
#pragma unroll
    for (int q = 0; q < Q; ++q) {
        h[q] = qhist[(b * Q + q) * BUCKET + t];
        c += h[q];
    }
    lds[t] = c;
    __syncthreads();
    for (int off = 1; off < BUCKET; off <<= 1) {
        int add = (t >= off) ? lds[t - off] : 0;
        __syncthreads();
        lds[t] += add;
        __syncthreads();
    }
    int j0 = bucket_base[b];
    int p = j0 + lds[t] - c;   // exclusive: row start for node (b,t)
    int run = p;
#pragma unroll
    for (int q = 0; q < Q; ++q) {
        qbase[(b * Q + q) * BUCKET + t] = run;
        run += h[q];
    }
    int node = b * BUCKET + t;
    float s2 = 0.f, s3 = 0.f, s4 = 0.f, sm0 = 0.f, sm1 = 0.f, sc = 0.f;
    if (node < n) {
        pos[node] = p;
        rowend[node] = p + c;
        float d = rsqrtf((float)(c + 1));
        dinv[node] = d;
        float x0 = x[node * 5 + 0], x1 = x[node * 5 + 1], x2 = x[node * 5 + 2];
        float x3 = x[node * 5 + 3], x4 = x[node * 5 + 4];
        float4 o;
        o.x = x0 * d; o.y = x1 * d; o.z = x2 * d; o.w = x3 * d;
        ((float4*)xs)[node * 2] = o;
        xs[node * 8 + 4] = x4 * d;
        s2 = x2; s3 = x3; s4 = x4;
        if (x2 == 1.0f) { sm0 = x0; sm1 = x1; sc = 1.f; }
    }
#pragma unroll
    for (int off = 32; off; off >>= 1) {
        s2 += __shfl_down(s2, off);
        s3 += __shfl_down(s3, off);
        s4 += __shfl_down(s4, off);
        sm0 += __shfl_down(sm0, off);
        sm1 += __shfl_down(sm1, off);
        sc += __shfl_down(sc, off);
    }
    if ((t & 63) == 0) {            // 4 waves -> LDS accumulate (cheap)
        atomicAdd(&gf6[0], s2);
        atomicAdd(&gf6[1], s3);
        atomicAdd(&gf6[2], s4);
        atomicAdd(&gf6[3], sm0);
        atomicAdd(&gf6[4], sm1);
        atomicAdd(&gf6[5], sc);
    }
    __syncthreads();
    if (t < 6) gfpart[b * 8 + t] = gf6[t];
}

// csrC: per-(bucket, slice) scatter into per-node CSR using private cursors
__global__ void k_csrC(const int* __restrict__ records, const int* __restrict__ bucket_base,
                       const int* __restrict__ qbase, int* __restrict__ ssrc) {
    __shared__ int cursor[BUCKET];
    int t = threadIdx.x, b = blockIdx.x, q = blockIdx.y;
    if (t < BUCKET) cursor[t] = qbase[(b * Q + q) * BUCKET + t];
    __syncthreads();
    int j0 = bucket_base[b], j1 = bucket_base[b + 1];
    int qlen = (j1 - j0 + Q - 1) / Q;
    int qs = j0 + q * qlen;
    int qe = min(qs + qlen, j1);
    for (int j = qs + t; j < qe; j += blockDim.x) {
        int rec = records[j];
        int slot = atomicAdd(&cursor[rec >> 17], 1);
        ssrc[slot] = rec & 131071;
    }
}

// 5-dim aggregation: agg5[i,:] = dinv[i] * ( sum_{s in N(i)} xs[s,:] + xs[i,:] )
__global__ void k_agg5(const int* __restrict__ pos, const int* __restrict__ rowend,
                       const int* __restrict__ ssrc, const float* __restrict__ dinv,
                       const float* __restrict__ xs, float* __restrict__ agg5, int n) {
    int i = blockIdx.x * blockDim.x + threadIdx.x;
    if (i >= n) return;
    const float4* xs4 = (const float4*)xs;
    float4 a = xs4[i * 2];            // self term
    float a4 = xs[i * 8 + 4];
    int beg = pos[i], end = rowend[i];
    int j = beg;
    for (; j + 1 < end; j += 2) {
        int s0 = ssrc[j], s1 = ssrc[j + 1];
        float4 v0 = xs4[s0 * 2]; float w0 = xs[s0 * 8 + 4];
        float4 v1 = xs4[s1 * 2]; float w1 = xs[s1 * 8 + 4];
        a.x += v0.x + v1.x; a.y += v0.y + v1.y;
        a.z += v0.z + v1.z; a.w += v0.w + v1.w;
        a4 += w0 + w1;
    }
    for (; j < end; ++j) {
        int s = ssrc[j];
        float4 v = xs4[s * 2];
        a.x += v.x; a.y += v.y; a.z += v.z; a.w += v.w;
        a4 += xs[s * 8 + 4];
    }
    float dd = dinv[i];
    float4 o; o.x = a.x * dd; o.y = a.y * dd; o.z = a.z * dd; o.w = a.w * dd;
    ((float4*)agg5)[i * 2] = o;
    agg5[i * 8 + 4] = a4 * dd;
}

// h1f8[i,f] = fp8_e4m3( dinv[i] * relu( agg5[i,:] @ W1[:,f] + b1[f] ) )
// Row n (one past the end) is written as zeros (safety for clamped indices).
__global__ void k_h1(const float* __restrict__ agg5, const float* __restrict__ W1,
                     const float* __restrict__ b1, const float* __restrict__ dinv,
                     unsigned char* __restrict__ h1f8, int n) {
    int t = blockIdx.x * blockDim.x + threadIdx.x;
    int i = t >> 6, f = t & 63;
    if (i > n) return;
    if (i == n) {                      // zero row
        h1f8[(size_t)i * 64 + f] = 0;  // fp8 0x00 == 0.0
        return;
    }
    float a0 = agg5[i * 8 + 0], a1 = agg5[i * 8 + 1], a2 = agg5[i * 8 + 2];
    float a3 = agg5[i * 8 + 3], a4 = agg5[i * 8 + 4];
    float v = a0 * W1[f] + a1 * W1[64 + f] + a2 * W1[128 + f]
            + a3 * W1[192 + f] + a4 * W1[256 + f] + b1[f];
    float hv = dinv[i] * fmaxf(v, 0.f);
    int packed = __builtin_amdgcn_cvt_pk_fp8_f32(hv, hv, 0, false);
    h1f8[(size_t)i * 64 + f] = (unsigned char)(packed & 0xFF);
}

// Layer 2 fully fused, 16 lanes per node x 4 fp8 features per lane.
// Wave = 4 nodes. Gather: 1 dword h1 load + 1 ssrc load per lane per step,
// divergent per-group loop (exec-masked, no clamps). Matmul: 64 shfl
// (ds_bpermute, LDS pipe) + 64 float4 W2 loads + 256 fmac.
__global__ __launch_bounds__(256)
void k_l2fuse(const int* __restrict__ pos, const int* __restrict__ rowend,
              const int* __restrict__ ssrc, const float* __restrict__ dinv,
              const unsigned char* __restrict__ h1f8, const float* __restrict__ W2,
              const float* __restrict__ b2, float* __restrict__ red, int n) {
    __shared__ float red64[64];
    int t = threadIdx.x;
    int lane = t & 63;
    int g = lane >> 4;               // node slot within task (0..3)
    int fl = lane & 15;              // dword index within 64B row
    int f0 = fl * 4;
    if (t < 64) red64[t] = 0.f;
    __syncthreads();
    const unsigned int* h1u = (const unsigned int*)h1f8;   // row = 16 dwords
    float4 bv = *(const float4*)&b2[f0];
    int gbase = lane & 48;
    int w = blockIdx.x * (blockDim.x >> 6) + (t >> 6);
    int nw = gridDim.x * (blockDim.x >> 6);
    float p0 = 0.f, p1 = 0.f, p2 = 0.f, p3 = 0.f;
    int nt = (n + 3) >> 2;
    for (int task = w; task < nt; task += nw) {
        int i = task * 4 + g;
        bool vi = i < n;
        int ci = vi ? i : n;                      // n -> zero row
        int p = vi ? pos[i] : 0;
        int e = vi ? rowend[i] : 0;
        unsigned int u = h1u[(size_t)ci * 16 + fl];
        float a0 = __builtin_amdgcn_cvt_f32_fp8(u, 0);
        float a1 = __builtin_amdgcn_cvt_f32_fp8(u, 1);
        float a2 = __builtin_amdgcn_cvt_f32_fp8(u, 2);
        float a3 = __builtin_amdgcn_cvt_f32_fp8(u, 3);
        int j = p;
        for (; j + 1 < e; j += 2) {               // per-group bounds, exec-masked
            int s0 = ssrc[j], s1 = ssrc[j + 1];
            unsigned int u0 = h1u[(size_t)s0 * 16 + fl];
            unsigned int u1 = h1u[(size_t)s1 * 16 + fl];
            a0 += __builtin_amdgcn_cvt_f32_fp8(u0, 0) + __builtin_amdgcn_cvt_f32_fp8(u1, 0);
            a1 += __builtin_amdgcn_cvt_f32_fp8(u0, 1) + __builtin_amdgcn_cvt_f32_fp8(u1, 1);
            a2 += __builtin_amdgcn_cvt_f32_fp8(u0, 2) + __builtin_amdgcn_cvt_f32_fp8(u1, 2);
            a3 += __builtin_amdgcn_cvt_f32_fp8(u0, 3) + __builtin_amdgcn_cvt_f32_fp8(u1, 3);
        }
        if (j < e) {
            int s = ssrc[j];
            unsigned int uu = h1u[(size_t)s * 16 + fl];
            a0 += __builtin_amdgcn_cvt_f32_fp8(uu, 0);
            a1 += __builtin_amdgcn_cvt_f32_fp8(uu, 1);
            a2 += __builtin_amdgcn_cvt_f32_fp8(uu, 2);
            a3 += __builtin_amdgcn_cvt_f32_fp8(uu, 3);
        }
        // matmul: q[c] = sum_k a_k(g) * W2[k][f0+c]; a_k at lane gbase+(k>>2),
        // register k&3 (compile-time via full unroll)
        float q0 = 0.f, q1 = 0.f, q2 = 0.f, q3 = 0.f;
#pragma unroll
        for (int k = 0; k < 64; ++k) {
            float ak;
            if ((k & 3) == 0) ak = a0;
            else if ((k & 3) == 1) ak = a1;
            else if ((k & 3) == 2) ak = a2;
            else ak = a3;
            ak = __shfl(ak, gbase + (k >> 2));
            float4 wv = *(const float4*)&W2[k * 64 + f0];
            q0 += ak * wv.x; q1 += ak * wv.y; q2 += ak * wv.z; q3 += ak * wv.w;
        }
        if (vi) {
            float dd = dinv[i];
            p0 += fmaxf(q0 * dd + bv.x, 0.f);
            p1 += fmaxf(q1 * dd + bv.y, 0.f);
            p2 += fmaxf(q2 * dd + bv.z, 0.f);
            p3 += fmaxf(q3 * dd + bv.w, 0.f);
        }
    }
    atomicAdd(&red64[f0 + 0], p0);
    atomicAdd(&red64[f0 + 1], p1);
    atomicAdd(&red64[f0 + 2], p2);
    atomicAdd(&red64[f0 + 3], p3);
    __syncthreads();
    if (t < 64) atomicAdd(&red[(blockIdx.x & (RCOPY - 1)) * 64 + t], red64[t]);
}

// Final head: emb = [mean(h2), gf(6)] (70), MLP 70->32->2, 2+3*sigmoid.
__global__ void k_head(const float* __restrict__ red, const float* __restrict__ gfpart,
                       const float* __restrict__ l1w, const float* __restrict__ l1b,
                       const float* __restrict__ l2w, const float* __restrict__ l2b,
                       float* __restrict__ out, int n, int NBK) {
    __shared__ float emb[70];
    __shared__ float hid[32];
    int t = threadIdx.x;
    if (t < 64) {
        float s = 0.f;
#pragma unroll
        for (int c = 0; c < RCOPY; ++c) s += red[c * 64 + t];
        emb[t] = s / (float)n;
    }
    float g0 = 0.f, g1 = 0.f, g2 = 0.f, g3 = 0.f, g4 = 0.f, g5 = 0.f;
    for (int b = t; b < NBK; b += 64) {
        g0 += gfpart[b * 8 + 0]; g1 += gfpart[b * 8 + 1];
        g2 += gfpart[b * 8 + 2]; g3 += gfpart[b * 8 + 3];
        g4 += gfpart[b * 8 + 4]; g5 += gfpart[b * 8 + 5];
    }
#pragma unroll
    for (int off = 32; off; off >>= 1) {
        g0 += __shfl_down(g0, off); g1 += __shfl_down(g1, off);
        g2 += __shfl_down(g2, off); g3 += __shfl_down(g3, off);
        g4 += __shfl_down(g4, off); g5 += __shfl_down(g5, off);
    }
    if (t == 0) {
        float cnt = g5;
        float safe = fmaxf(cnt, 1.f);
        emb[64] = g0;                       // n_comp
        emb[65] = g1;                       // n_and
        emb[66] = g2;                       // n_or
        emb[67] = g1 + g2;                  // depth
        emb[68] = cnt > 0.f ? g3 / safe : 0.f;   // avg_lambda
        emb[69] = cnt > 0.f ? g4 / safe : 0.f;   // avg_mu
    }
    __syncthreads();
    if (t < 32) {
        float acc = l1b[t];
#pragma unroll
        for (int k = 0; k < 70; ++k) acc += emb[k] * l1w[k * 32 + t];
        hid[t] = fmaxf(acc, 0.f);
    }
    __syncthreads();
    if (t < 2) {
        float acc = l2b[t];
#pragma unroll
        for (int j = 0; j < 32; ++j) acc += hid[j] * l2w[j * 2 + t];
        out[t] = 2.0f + 3.0f / (1.0f + expf(-acc));
    }
}

extern "C" void kernel_launch(void* const* d_in, const int* in_sizes, int n_in,
                              void* d_out, int out_size, void* d_ws, size_t ws_size,
                              hipStream_t stream) {
    const float* x   = (const float*)d_in[0];
    const int*   ei  = (const int*)d_in[1];
    const float* w1  = (const float*)d_in[2];
    const float* b1  = (const float*)d_in[3];
    const float* w2  = (const float*)d_in[4];
    const float* b2  = (const float*)d_in[5];
    const float* l1w = (const float*)d_in[6];
    const float* l1b = (const float*)d_in[7];
    const float* l2w = (const float*)d_in[8];
    const float* l2b = (const float*)d_in[9];

    const int n = in_sizes[0] / 5;
    const int E = in_sizes[1] / 2;
    const int* src = ei;
    const int* dst = ei + E;

    const int NBK = (n + BUCKET - 1) / BUCKET;   // 391 buckets
    const int NCH = NCHV;                         // 2048 edge chunks
    const int chunk = (E + NCH - 1) / NCH;

    size_t nf = (size_t)(n + 1) * 64;             // +1: zero row at index n
    unsigned char* h1f8 = (unsigned char*)d_ws;       // (N+1) x 64 fp8
    float* xs          = (float*)(h1f8 + ((nf + 255) & ~(size_t)255));
    float* agg5        = xs + (size_t)n * 8;          // N x 8 (padded)
    float* dinv        = agg5 + (size_t)n * 8;
    float* red         = dinv + n;                    // RCOPY*64 floats
    float* gfpart      = red + RCOPY * 64;            // NBK*8 floats
    int*   pos         = (int*)(gfpart + (MAXB * 8));
    int*   rowend      = pos + n;
    int*   btot        = rowend + n;                  // MAXB ints
    int*   bucket_base = btot + MAXB;                 // NBK+1
    int*   qhist       = bucket_base + (MAXB + 8);    // NBK*Q*256
    int*   qbase       = qhist + NBK * Q * BUCKET;    // NBK*Q*256
    int*   gcounts     = qbase + NBK * Q * BUCKET;    // NCH*NBK
    int*   records     = gcounts + NCH * NBK;         // E ints
    int*   ssrc        = records + E;                 // E ints, per-node CSR

    k_hist<<<NCH, 512, 0, stream>>>(dst, E, chunk, gcounts, NBK);
    k_colsum<<<NBK, 256, 0, stream>>>(gcounts, btot, NBK, NCH);
    k_scanA<<<1, MAXB, 0, stream>>>(btot, bucket_base, red, NBK);
    k_scanB<<<NBK, 512, 0, stream>>>(gcounts, bucket_base, NBK, NCH);
    k_bucketize<<<NCH, 512, 0, stream>>>(src, dst, E, chunk, gcounts, records, NBK);

    dim3 qgrid(NBK, Q);
    k_csrA<<<qgrid, 512, 0, stream>>>(records, bucket_base, qhist);
    k_csrB<<<NBK, BUCKET, 0, stream>>>(qhist, bucket_base, x, qbase, pos, rowend,
                                       dinv, xs, gfpart, n);
    k_csrC<<<qgrid, 512, 0, stream>>>(records, bucket_base, qbase, ssrc);

    k_agg5<<<(n + 255) / 256, 256, 0, stream>>>(pos, rowend, ssrc, dinv, xs, agg5, n);
    k_h1<<<(int)((nf + 255) / 256), 256, 0, stream>>>(agg5, w1, b1, dinv, h1f8, n);

    k_l2fuse<<<4096, 256, 0, stream>>>(pos, rowend, ssrc, dinv, h1f8, w2, b2, red, n);

    k_head<<<1, 64, 0, stream>>>(red, gfpart, l1w, l1b, l2w, l2b, (float*)d_out, n, NBK);
}

// Round 20
// 280.676 us; speedup vs baseline: 2.2057x; 2.2057x over previous
//
#include <hip/hip_runtime.h>
#include <hip/hip_bf16.h>
#include <math.h>

// ---------------------------------------------------------------------------
// GCN predictor: 2x GCNConv(relu) -> mean pool + global feats -> MLP head
// N=100K nodes, E=3.2M directed edges, H=64.
// R20: revert to R17 (best: 257.7us). fp8 h1s (64B rows), zero-row padding,
// 4-stream/36-VGPR l2fuse with shfl matmul (ds_bpermute on LDS pipe).
// Only change vs R17: l2fuse grid sized to exactly 1 task/wave.
// Structural lessons (all measured):
//  - 4-stream/low-VGPR l2fuse is the optimum: 8-stream(R13), W2-VGPR(R13),
//    half-wave-packed(R15), readlane(R18), dword-lane full-unroll(R19) all
//    regressed via occupancy loss, pipe imbalance, or scratch spills.
//  - no hot-address device atomics (~80ns/op serialized, R11).
//  - no global atomics on the edge path (~100MB write-through, R1/R9).
//  - gather is NOT BW-bound (R6: bf16 halved traffic, no speedup; R17: fp8
//    halved again, -6us) -- it is issue/latency-balanced at 62% VALUBusy.
// ---------------------------------------------------------------------------

#define BUCKET 256
#define MAXB   512    // max buckets (needs n <= 131072)
#define NCHV   2048   // edge chunks
#define Q      8      // csr record slices per bucket
#define RCOPY  32     // spread copies for the mean-pool accumulator

// per-chunk bucket histogram: gcounts[chunk*NBK + bucket]
__global__ void k_hist(const int* __restrict__ dst, int E, int chunk,
                       int* __restrict__ gcounts, int NBK) {
    __shared__ int lcnt[MAXB];
    for (int i = threadIdx.x; i < NBK; i += blockDim.x) lcnt[i] = 0;
    __syncthreads();
    int e0 = blockIdx.x * chunk;
    int e1 = min(e0 + chunk, E);
    for (int e = e0 + threadIdx.x; e < e1; e += blockDim.x)
        atomicAdd(&lcnt[dst[e] >> 8], 1);
    __syncthreads();
    for (int b = threadIdx.x; b < NBK; b += blockDim.x)
        gcounts[blockIdx.x * NBK + b] = lcnt[b];
}

// per-bucket totals: btot[b] = sum_c gcounts[c*NBK+b]
__global__ void k_colsum(const int* __restrict__ gcounts, int* __restrict__ btot,
                         int NBK, int NCH) {
    __shared__ int lds[256];
    int b = blockIdx.x, t = threadIdx.x;
    int s = 0;
    for (int c = t; c < NCH; c += 256) s += gcounts[c * NBK + b];
    lds[t] = s;
    __syncthreads();
    for (int off = 128; off; off >>= 1) {
        if (t < off) lds[t] += lds[t + off];
        __syncthreads();
    }
    if (t == 0) btot[b] = lds[0];
}

// single block: bucket_base = exclusive scan of btot; zero-init red copies;
// set the dummy CSR slot ssrc[E] = n (points at h1f8's zero row)
__global__ void k_scanA(const int* __restrict__ btot, int* __restrict__ bucket_base,
                        float* __restrict__ red, int* __restrict__ ssrc,
                        int E, int n, int NBK) {
    __shared__ int lds[MAXB];
    int t = threadIdx.x;
    for (int i = t; i < RCOPY * 64; i += MAXB) red[i] = 0.f;
    if (t == 0) ssrc[E] = n;
    int v = (t < NBK) ? btot[t] : 0;
    lds[t] = v;
    __syncthreads();
    for (int off = 1; off < MAXB; off <<= 1) {
        int add = (t >= off) ? lds[t - off] : 0;
        __syncthreads();
        lds[t] += add;
        __syncthreads();
    }
    if (t < NBK) bucket_base[t] = lds[t] - v;
    if (t == NBK - 1) bucket_base[NBK] = lds[t];
}

// per bucket: exclusive scan of gcounts[c*NBK+b] over c, in place
__global__ void k_scanB(int* __restrict__ gcounts, const int* __restrict__ bucket_base,
                        int NBK, int NCH) {
    __shared__ int lds[512];
    int b = blockIdx.x, t = threadIdx.x;
    int carry = bucket_base[b];
    for (int base = 0; base < NCH; base += 512) {
        int c = base + t;
        int v = (c < NCH) ? gcounts[c * NBK + b] : 0;
        lds[t] = v;
        __syncthreads();
        for (int off = 1; off < 512; off <<= 1) {
            int add = (t >= off) ? lds[t - off] : 0;
            __syncthreads();
            lds[t] += add;
            __syncthreads();
        }
        if (c < NCH) gcounts[c * NBK + b] = carry + lds[t] - v;
        int tot = lds[511];
        __syncthreads();
        carry += tot;
    }
}

// scatter packed records (local_d<<17 | src) into bucket-grouped order
__global__ void k_bucketize(const int* __restrict__ src, const int* __restrict__ dst,
                            int E, int chunk, const int* __restrict__ gcounts,
                            int* __restrict__ records, int NBK) {
    __shared__ int lcur[MAXB];
    for (int b = threadIdx.x; b < NBK; b += blockDim.x)
        lcur[b] = gcounts[blockIdx.x * NBK + b];
    __syncthreads();
    int e0 = blockIdx.x * chunk;
    int e1 = min(e0 + chunk, E);
    for (int e = e0 + threadIdx.x; e < e1; e += blockDim.x) {
        int d = dst[e];
        int b = d >> 8;
        int rec = ((d & 255) << 17) | src[e];
        int slot = atomicAdd(&lcur[b], 1);
        records[slot] = rec;
    }
}

// csrA: per-(bucket, slice) histogram of local nodes -> qhist
__global__ void k_csrA(const int* __restrict__ records, const int* __restrict__ bucket_base,
                       int* __restrict__ qhist) {
    __shared__ int cnt[BUCKET];
    int t = threadIdx.x, b = blockIdx.x, q = blockIdx.y;
    if (t < BUCKET) cnt[t] = 0;
    __syncthreads();
    int j0 = bucket_base[b], j1 = bucket_base[b + 1];
    int qlen = (j1 - j0 + Q - 1) / Q;
    int qs = j0 + q * qlen;
    int qe = min(qs + qlen, j1);
    for (int j = qs + t; j < qe; j += blockDim.x)
        atomicAdd(&cnt[records[j] >> 17], 1);
    __syncthreads();
    if (t < BUCKET) qhist[(b * Q + q) * BUCKET + t] = cnt[t];
}

// csrB: per-bucket scan of summed slice histograms -> pos/rowend/dinv/xs,
// per-slice cursor bases qbase, per-block gf partials (no hot atomics)
__global__ void k_csrB(const int* __restrict__ qhist, const int* __restrict__ bucket_base,
                       const float* __restrict__ x,
                       int* __restrict__ qbase, int* __restrict__ pos,
                       int* __restrict__ rowend, float* __restrict__ dinv,
                       float* __restrict__ xs, float* __restrict__ gfpart, int n) {
    __shared__ int lds[BUCKET];
    __shared__ float gf6[8];
    int t = threadIdx.x, b = blockIdx.x;
    if (t < 8) gf6[t] = 0.f;
    int h[Q];
    int c = 0;
#pragma unroll
    for (int q = 0; q < Q; ++q) {
        h[q] = qhist[(b * Q + q) * BUCKET + t];
        c += h[q];
    }
    lds[t] = c;
    __syncthreads();
    for (int off = 1; off < BUCKET; off <<= 1) {
        int add = (t >= off) ? lds[t - off] : 0;
        __syncthreads();
        lds[t] += add;
        __syncthreads();
    }
    int j0 = bucket_base[b];
    int p = j0 + lds[t] - c;   // exclusive: row start for node (b,t)
    int run = p;
#pragma unroll
    for (int q = 0; q < Q; ++q) {
        qbase[(b * Q + q) * BUCKET + t] = run;
        run += h[q];
    }
    int node = b * BUCKET + t;
    float s2 = 0.f, s3 = 0.f, s4 = 0.f, sm0 = 0.f, sm1 = 0.f, sc = 0.f;
    if (node < n) {
        pos[node] = p;
        rowend[node] = p + c;
        float d = rsqrtf((float)(c + 1));
        dinv[node] = d;
        float x0 = x[node * 5 + 0], x1 = x[node * 5 + 1], x2 = x[node * 5 + 2];
        float x3 = x[node * 5 + 3], x4 = x[node * 5 + 4];
        float4 o;
        o.x = x0 * d; o.y = x1 * d; o.z = x2 * d; o.w = x3 * d;
        ((float4*)xs)[node * 2] = o;
        xs[node * 8 + 4] = x4 * d;
        s2 = x2; s3 = x3; s4 = x4;
        if (x2 == 1.0f) { sm0 = x0; sm1 = x1; sc = 1.f; }
    }
#pragma unroll
    for (int off = 32; off; off >>= 1) {
        s2 += __shfl_down(s2, off);
        s3 += __shfl_down(s3, off);
        s4 += __shfl_down(s4, off);
        sm0 += __shfl_down(sm0, off);
        sm1 += __shfl_down(sm1, off);
        sc += __shfl_down(sc, off);
    }
    if ((t & 63) == 0) {            // 4 waves -> LDS accumulate (cheap)
        atomicAdd(&gf6[0], s2);
        atomicAdd(&gf6[1], s3);
        atomicAdd(&gf6[2], s4);
        atomicAdd(&gf6[3], sm0);
        atomicAdd(&gf6[4], sm1);
        atomicAdd(&gf6[5], sc);
    }
    __syncthreads();
    if (t < 6) gfpart[b * 8 + t] = gf6[t];
}

// csrC: per-(bucket, slice) scatter into per-node CSR using private cursors
__global__ void k_csrC(const int* __restrict__ records, const int* __restrict__ bucket_base,
                       const int* __restrict__ qbase, int* __restrict__ ssrc) {
    __shared__ int cursor[BUCKET];
    int t = threadIdx.x, b = blockIdx.x, q = blockIdx.y;
    if (t < BUCKET) cursor[t] = qbase[(b * Q + q) * BUCKET + t];
    __syncthreads();
    int j0 = bucket_base[b], j1 = bucket_base[b + 1];
    int qlen = (j1 - j0 + Q - 1) / Q;
    int qs = j0 + q * qlen;
    int qe = min(qs + qlen, j1);
    for (int j = qs + t; j < qe; j += blockDim.x) {
        int rec = records[j];
        int slot = atomicAdd(&cursor[rec >> 17], 1);
        ssrc[slot] = rec & 131071;
    }
}

// 5-dim aggregation: agg5[i,:] = dinv[i] * ( sum_{s in N(i)} xs[s,:] + xs[i,:] )
__global__ void k_agg5(const int* __restrict__ pos, const int* __restrict__ rowend,
                       const int* __restrict__ ssrc, const float* __restrict__ dinv,
                       const float* __restrict__ xs, float* __restrict__ agg5, int n) {
    int i = blockIdx.x * blockDim.x + threadIdx.x;
    if (i >= n) return;
    const float4* xs4 = (const float4*)xs;
    float4 a = xs4[i * 2];            // self term
    float a4 = xs[i * 8 + 4];
    int beg = pos[i], end = rowend[i];
    int j = beg;
    for (; j + 1 < end; j += 2) {
        int s0 = ssrc[j], s1 = ssrc[j + 1];
        float4 v0 = xs4[s0 * 2]; float w0 = xs[s0 * 8 + 4];
        float4 v1 = xs4[s1 * 2]; float w1 = xs[s1 * 8 + 4];
        a.x += v0.x + v1.x; a.y += v0.y + v1.y;
        a.z += v0.z + v1.z; a.w += v0.w + v1.w;
        a4 += w0 + w1;
    }
    for (; j < end; ++j) {
        int s = ssrc[j];
        float4 v = xs4[s * 2];
        a.x += v.x; a.y += v.y; a.z += v.z; a.w += v.w;
        a4 += xs[s * 8 + 4];
    }
    float dd = dinv[i];
    float4 o; o.x = a.x * dd; o.y = a.y * dd; o.z = a.z * dd; o.w = a.w * dd;
    ((float4*)agg5)[i * 2] = o;
    agg5[i * 8 + 4] = a4 * dd;
}

// h1f8[i,f] = fp8_e4m3( dinv[i] * relu( agg5[i,:] @ W1[:,f] + b1[f] ) )
// Row n (one past the end) is written as zeros: the dummy row for padding.
__global__ void k_h1(const float* __restrict__ agg5, const float* __restrict__ W1,
                     const float* __restrict__ b1, const float* __restrict__ dinv,
                     unsigned char* __restrict__ h1f8, int n) {
    int t = blockIdx.x * blockDim.x + threadIdx.x;
    int i = t >> 6, f = t & 63;
    if (i > n) return;
    if (i == n) {                      // zero row for the dummy CSR slot
        h1f8[(size_t)i * 64 + f] = 0;  // fp8 0x00 == 0.0
        return;
    }
    float a0 = agg5[i * 8 + 0], a1 = agg5[i * 8 + 1], a2 = agg5[i * 8 + 2];
    float a3 = agg5[i * 8 + 3], a4 = agg5[i * 8 + 4];
    float v = a0 * W1[f] + a1 * W1[64 + f] + a2 * W1[128 + f]
            + a3 * W1[192 + f] + a4 * W1[256 + f] + b1[f];
    float hv = dinv[i] * fmaxf(v, 0.f);
    int packed = __builtin_amdgcn_cvt_pk_fp8_f32(hv, hv, 0, false);
    h1f8[(size_t)i * 64 + f] = (unsigned char)(packed & 0xFF);
}

// Layer 2 fully fused, 4 nodes per wave interleaved; fp8 rows (64B = 1 line),
// zero-row padding -> unconditional adds; RCOPY-spread accumulation.
// Exactly one task per wave (grid-sized); grid-stride kept for safety.
__global__ __launch_bounds__(256)
void k_l2fuse(const int* __restrict__ pos, const int* __restrict__ rowend,
              const int* __restrict__ ssrc, const float* __restrict__ dinv,
              const unsigned char* __restrict__ h1f8, const float* __restrict__ W2,
              const float* __restrict__ b2, float* __restrict__ red, int n, int E) {
    __shared__ float red64[64];
    int t = threadIdx.x, f = t & 63;
    if (t < 64) red64[t] = 0.f;
    __syncthreads();
    int w = blockIdx.x * (blockDim.x >> 6) + (t >> 6);
    int nw = gridDim.x * (blockDim.x >> 6);
    float bf = b2[f];
    float psum = 0.f;
    int nt = (n + 3) >> 2;
    for (int task = w; task < nt; task += nw) {
        int i0 = task * 4, i1 = i0 + 1, i2 = i0 + 2, i3 = i0 + 3;
        bool v1 = i1 < n, v2 = i2 < n, v3 = i3 < n;
        int p0 = pos[i0],            e0 = rowend[i0];
        int p1 = v1 ? pos[i1] : 0,   e1 = v1 ? rowend[i1] : 0;
        int p2 = v2 ? pos[i2] : 0,   e2 = v2 ? rowend[i2] : 0;
        int p3 = v3 ? pos[i3] : 0,   e3 = v3 ? rowend[i3] : 0;
        float a0 = __builtin_amdgcn_cvt_f32_fp8(h1f8[(size_t)i0 * 64 + f], 0);
        float a1 = v1 ? __builtin_amdgcn_cvt_f32_fp8(h1f8[(size_t)i1 * 64 + f], 0) : 0.f;
        float a2 = v2 ? __builtin_amdgcn_cvt_f32_fp8(h1f8[(size_t)i2 * 64 + f], 0) : 0.f;
        float a3 = v3 ? __builtin_amdgcn_cvt_f32_fp8(h1f8[(size_t)i3 * 64 + f], 0) : 0.f;
        int len = max(max(e0 - p0, e1 - p1), max(e2 - p2, e3 - p3));
#pragma unroll 2
        for (int m = 0; m < len; ++m) {
            int j0 = p0 + m, j1 = p1 + m, j2 = p2 + m, j3 = p3 + m;
            int s0 = ssrc[j0 < e0 ? j0 : E];   // dummy slot -> zero row
            int s1 = ssrc[j1 < e1 ? j1 : E];
            int s2 = ssrc[j2 < e2 ? j2 : E];
            int s3 = ssrc[j3 < e3 ? j3 : E];
            a0 += __builtin_amdgcn_cvt_f32_fp8(h1f8[(size_t)s0 * 64 + f], 0);
            a1 += __builtin_amdgcn_cvt_f32_fp8(h1f8[(size_t)s1 * 64 + f], 0);
            a2 += __builtin_amdgcn_cvt_f32_fp8(h1f8[(size_t)s2 * 64 + f], 0);
            a3 += __builtin_amdgcn_cvt_f32_fp8(h1f8[(size_t)s3 * 64 + f], 0);
        }
        // conv2: out_k[f] = relu( dinv * sum_kk a_k[kk]*W2[kk,f] + b2[f] )
        float q0 = 0.f, q1 = 0.f, q2 = 0.f, q3 = 0.f;
#pragma unroll 8
        for (int k = 0; k < 64; ++k) {
            float w2v = W2[k * 64 + f];
            q0 += __shfl(a0, k) * w2v;
            q1 += __shfl(a1, k) * w2v;
            q2 += __shfl(a2, k) * w2v;
            q3 += __shfl(a3, k) * w2v;
        }
        psum += fmaxf(q0 * dinv[i0] + bf, 0.f);
        if (v1) psum += fmaxf(q1 * dinv[i1] + bf, 0.f);
        if (v2) psum += fmaxf(q2 * dinv[i2] + bf, 0.f);
        if (v3) psum += fmaxf(q3 * dinv[i3] + bf, 0.f);
    }
    atomicAdd(&red64[f], psum);
    __syncthreads();
    if (t < 64) atomicAdd(&red[(blockIdx.x & (RCOPY - 1)) * 64 + t], red64[t]);
}

// Final head: emb = [mean(h2), gf(6)] (70), MLP 70->32->2, 2+3*sigmoid.
__global__ void k_head(const float* __restrict__ red, const float* __restrict__ gfpart,
                       const float* __restrict__ l1w, const float* __restrict__ l1b,
                       const float* __restrict__ l2w, const float* __restrict__ l2b,
                       float* __restrict__ out, int n, int NBK) {
    __shared__ float emb[70];
    __shared__ float hid[32];
    int t = threadIdx.x;
    if (t < 64) {
        float s = 0.f;
#pragma unroll
        for (int c = 0; c < RCOPY; ++c) s += red[c * 64 + t];
        emb[t] = s / (float)n;
    }
    float g0 = 0.f, g1 = 0.f, g2 = 0.f, g3 = 0.f, g4 = 0.f, g5 = 0.f;
    for (int b = t; b < NBK; b += 64) {
        g0 += gfpart[b * 8 + 0]; g1 += gfpart[b * 8 + 1];
        g2 += gfpart[b * 8 + 2]; g3 += gfpart[b * 8 + 3];
        g4 += gfpart[b * 8 + 4]; g5 += gfpart[b * 8 + 5];
    }
#pragma unroll
    for (int off = 32; off; off >>= 1) {
        g0 += __shfl_down(g0, off); g1 += __shfl_down(g1, off);
        g2 += __shfl_down(g2, off); g3 += __shfl_down(g3, off);
        g4 += __shfl_down(g4, off); g5 += __shfl_down(g5, off);
    }
    if (t == 0) {
        float cnt = g5;
        float safe = fmaxf(cnt, 1.f);
        emb[64] = g0;                       // n_comp
        emb[65] = g1;                       // n_and
        emb[66] = g2;                       // n_or
        emb[67] = g1 + g2;                  // depth
        emb[68] = cnt > 0.f ? g3 / safe : 0.f;   // avg_lambda
        emb[69] = cnt > 0.f ? g4 / safe : 0.f;   // avg_mu
    }
    __syncthreads();
    if (t < 32) {
        float acc = l1b[t];
#pragma unroll
        for (int k = 0; k < 70; ++k) acc += emb[k] * l1w[k * 32 + t];
        hid[t] = fmaxf(acc, 0.f);
    }
    __syncthreads();
    if (t < 2) {
        float acc = l2b[t];
#pragma unroll
        for (int j = 0; j < 32; ++j) acc += hid[j] * l2w[j * 2 + t];
        out[t] = 2.0f + 3.0f / (1.0f + expf(-acc));
    }
}

extern "C" void kernel_launch(void* const* d_in, const int* in_sizes, int n_in,
                              void* d_out, int out_size, void* d_ws, size_t ws_size,
                              hipStream_t stream) {
    const float* x   = (const float*)d_in[0];
    const int*   ei  = (const int*)d_in[1];
    const float* w1  = (const float*)d_in[2];
    const float* b1  = (const float*)d_in[3];
    const float* w2  = (const float*)d_in[4];
    const float* b2  = (const float*)d_in[5];
    const float* l1w = (const float*)d_in[6];
    const float* l1b = (const float*)d_in[7];
    const float* l2w = (const float*)d_in[8];
    const float* l2b = (const float*)d_in[9];

    const int n = in_sizes[0] / 5;
    const int E = in_sizes[1] / 2;
    const int* src = ei;
    const int* dst = ei + E;

    const int NBK = (n + BUCKET - 1) / BUCKET;   // 391 buckets
    const int NCH = NCHV;                         // 2048 edge chunks
    const int chunk = (E + NCH - 1) / NCH;

    size_t nf = (size_t)(n + 1) * 64;             // +1: zero row at index n
    unsigned char* h1f8 = (unsigned char*)d_ws;       // (N+1) x 64 fp8
    float* xs          = (float*)(h1f8 + ((nf + 255) & ~(size_t)255));
    float* agg5        = xs + (size_t)n * 8;          // N x 8 (padded)
    float* dinv        = agg5 + (size_t)n * 8;
    float* red         = dinv + n;                    // RCOPY*64 floats
    float* gfpart      = red + RCOPY * 64;            // NBK*8 floats
    int*   pos         = (int*)(gfpart + (MAXB * 8));
    int*   rowend      = pos + n;
    int*   btot        = rowend + n;                  // MAXB ints
    int*   bucket_base = btot + MAXB;                 // NBK+1
    int*   qhist       = bucket_base + (MAXB + 8);    // NBK*Q*256
    int*   qbase       = qhist + NBK * Q * BUCKET;    // NBK*Q*256
    int*   gcounts     = qbase + NBK * Q * BUCKET;    // NCH*NBK
    int*   records     = gcounts + NCH * NBK;         // E ints
    int*   ssrc        = records + E;                 // E+1 ints (slot E = dummy)

    k_hist<<<NCH, 512, 0, stream>>>(dst, E, chunk, gcounts, NBK);
    k_colsum<<<NBK, 256, 0, stream>>>(gcounts, btot, NBK, NCH);
    k_scanA<<<1, MAXB, 0, stream>>>(btot, bucket_base, red, ssrc, E, n, NBK);
    k_scanB<<<NBK, 512, 0, stream>>>(gcounts, bucket_base, NBK, NCH);
    k_bucketize<<<NCH, 512, 0, stream>>>(src, dst, E, chunk, gcounts, records, NBK);

    dim3 qgrid(NBK, Q);
    k_csrA<<<qgrid, 512, 0, stream>>>(records, bucket_base, qhist);
    k_csrB<<<NBK, BUCKET, 0, stream>>>(qhist, bucket_base, x, qbase, pos, rowend,
                                       dinv, xs, gfpart, n);
    k_csrC<<<qgrid, 512, 0, stream>>>(records, bucket_base, qbase, ssrc);

    k_agg5<<<(n + 255) / 256, 256, 0, stream>>>(pos, rowend, ssrc, dinv, xs, agg5, n);
    k_h1<<<(int)((nf + 255) / 256), 256, 0, stream>>>(agg5, w1, b1, dinv, h1f8, n);

    const int nt = (n + 3) >> 2;                  // tasks (4 nodes each)
    const int l2blocks = (nt + 3) / 4;            // exactly 1 task per wave
    k_l2fuse<<<l2blocks, 256, 0, stream>>>(pos, rowend, ssrc, dinv, h1f8, w2, b2,
                                           red, n, E);

    k_head<<<1, 64, 0, stream>>>(red, gfpart, l1w, l1b, l2w, l2b, (float*)d_out, n, NBK);
}

// Round 21
// 257.627 us; speedup vs baseline: 2.4030x; 1.0895x over previous
//
#include <hip/hip_runtime.h>
#include <hip/hip_bf16.h>
#include <math.h>

// ---------------------------------------------------------------------------
// GCN predictor: 2x GCNConv(relu) -> mean pool + global feats -> MLP head
// N=100K nodes, E=3.2M directed edges, H=64.
// R21: restore R17 exactly (measured best: 257.7us). fp8 h1s (64B rows),
// zero-row padding, 4-stream/36-VGPR l2fuse with shfl matmul, 4096-block
// grid-stride (R20 showed 1-task/wave grids amortize per-wave overhead worse).
// Structural lessons (all measured):
//  - 4-stream/low-VGPR l2fuse is the optimum: 8-stream(R13), W2-VGPR(R13),
//    half-wave-packed(R15), readlane(R18), dword-lane full-unroll(R19, spills),
//    1-task grid(R20) all regressed.
//  - no hot-address device atomics (~80ns/op serialized, R11).
//  - no global atomics on the edge path (~100MB write-through, R1/R9).
//  - gather is NOT BW-bound (R6/R17: traffic halved twice, dur unchanged)
//    -- issue/latency-balanced at ~62% VALUBusy, 64% occupancy.
// ---------------------------------------------------------------------------

#define BUCKET 256
#define MAXB   512    // max buckets (needs n <= 131072)
#define NCHV   2048   // edge chunks
#define Q      8      // csr record slices per bucket
#define RCOPY  32     // spread copies for the mean-pool accumulator

// per-chunk bucket histogram: gcounts[chunk*NBK + bucket]
__global__ void k_hist(const int* __restrict__ dst, int E, int chunk,
                       int* __restrict__ gcounts, int NBK) {
    __shared__ int lcnt[MAXB];
    for (int i = threadIdx.x; i < NBK; i += blockDim.x) lcnt[i] = 0;
    __syncthreads();
    int e0 = blockIdx.x * chunk;
    int e1 = min(e0 + chunk, E);
    for (int e = e0 + threadIdx.x; e < e1; e += blockDim.x)
        atomicAdd(&lcnt[dst[e] >> 8], 1);
    __syncthreads();
    for (int b = threadIdx.x; b < NBK; b += blockDim.x)
        gcounts[blockIdx.x * NBK + b] = lcnt[b];
}

// per-bucket totals: btot[b] = sum_c gcounts[c*NBK+b]
__global__ void k_colsum(const int* __restrict__ gcounts, int* __restrict__ btot,
                         int NBK, int NCH) {
    __shared__ int lds[256];
    int b = blockIdx.x, t = threadIdx.x;
    int s = 0;
    for (int c = t; c < NCH; c += 256) s += gcounts[c * NBK + b];
    lds[t] = s;
    __syncthreads();
    for (int off = 128; off; off >>= 1) {
        if (t < off) lds[t] += lds[t + off];
        __syncthreads();
    }
    if (t == 0) btot[b] = lds[0];
}

// single block: bucket_base = exclusive scan of btot; zero-init red copies;
// set the dummy CSR slot ssrc[E] = n (points at h1f8's zero row)
__global__ void k_scanA(const int* __restrict__ btot, int* __restrict__ bucket_base,
                        float* __restrict__ red, int* __restrict__ ssrc,
                        int E, int n, int NBK) {
    __shared__ int lds[MAXB];
    int t = threadIdx.x;
    for (int i = t; i < RCOPY * 64; i += MAXB) red[i] = 0.f;
    if (t == 0) ssrc[E] = n;
    int v = (t < NBK) ? btot[t] : 0;
    lds[t] = v;
    __syncthreads();
    for (int off = 1; off < MAXB; off <<= 1) {
        int add = (t >= off) ? lds[t - off] : 0;
        __syncthreads();
        lds[t] += add;
        __syncthreads();
    }
    if (t < NBK) bucket_base[t] = lds[t] - v;
    if (t == NBK - 1) bucket_base[NBK] = lds[t];
}

// per bucket: exclusive scan of gcounts[c*NBK+b] over c, in place
__global__ void k_scanB(int* __restrict__ gcounts, const int* __restrict__ bucket_base,
                        int NBK, int NCH) {
    __shared__ int lds[512];
    int b = blockIdx.x, t = threadIdx.x;
    int carry = bucket_base[b];
    for (int base = 0; base < NCH; base += 512) {
        int c = base + t;
        int v = (c < NCH) ? gcounts[c * NBK + b] : 0;
        lds[t] = v;
        __syncthreads();
        for (int off = 1; off < 512; off <<= 1) {
            int add = (t >= off) ? lds[t - off] : 0;
            __syncthreads();
            lds[t] += add;
            __syncthreads();
        }
        if (c < NCH) gcounts[c * NBK + b] = carry + lds[t] - v;
        int tot = lds[511];
        __syncthreads();
        carry += tot;
    }
}

// scatter packed records (local_d<<17 | src) into bucket-grouped order
__global__ void k_bucketize(const int* __restrict__ src, const int* __restrict__ dst,
                            int E, int chunk, const int* __restrict__ gcounts,
                            int* __restrict__ records, int NBK) {
    __shared__ int lcur[MAXB];
    for (int b = threadIdx.x; b < NBK; b += blockDim.x)
        lcur[b] = gcounts[blockIdx.x * NBK + b];
    __syncthreads();
    int e0 = blockIdx.x * chunk;
    int e1 = min(e0 + chunk, E);
    for (int e = e0 + threadIdx.x; e < e1; e += blockDim.x) {
        int d = dst[e];
        int b = d >> 8;
        int rec = ((d & 255) << 17) | src[e];
        int slot = atomicAdd(&lcur[b], 1);
        records[slot] = rec;
    }
}

// csrA: per-(bucket, slice) histogram of local nodes -> qhist
__global__ void k_csrA(const int* __restrict__ records, const int* __restrict__ bucket_base,
                       int* __restrict__ qhist) {
    __shared__ int cnt[BUCKET];
    int t = threadIdx.x, b = blockIdx.x, q = blockIdx.y;
    if (t < BUCKET) cnt[t] = 0;
    __syncthreads();
    int j0 = bucket_base[b], j1 = bucket_base[b + 1];
    int qlen = (j1 - j0 + Q - 1) / Q;
    int qs = j0 + q * qlen;
    int qe = min(qs + qlen, j1);
    for (int j = qs + t; j < qe; j += blockDim.x)
        atomicAdd(&cnt[records[j] >> 17], 1);
    __syncthreads();
    if (t < BUCKET) qhist[(b * Q + q) * BUCKET + t] = cnt[t];
}

// csrB: per-bucket scan of summed slice histograms -> pos/rowend/dinv/xs,
// per-slice cursor bases qbase, per-block gf partials (no hot atomics)
__global__ void k_csrB(const int* __restrict__ qhist, const int* __restrict__ bucket_base,
                       const float* __restrict__ x,
                       int* __restrict__ qbase, int* __restrict__ pos,
                       int* __restrict__ rowend, float* __restrict__ dinv,
                       float* __restrict__ xs, float* __restrict__ gfpart, int n) {
    __shared__ int lds[BUCKET];
    __shared__ float gf6[8];
    int t = threadIdx.x, b = blockIdx.x;
    if (t < 8) gf6[t] = 0.f;
    int h[Q];
    int c = 0;
#pragma unroll
    for (int q = 0; q < Q; ++q) {
        h[q] = qhist[(b * Q + q) * BUCKET + t];
        c += h[q];
    }
    lds[t] = c;
    __syncthreads();
    for (int off = 1; off < BUCKET; off <<= 1) {
        int add = (t >= off) ? lds[t - off] : 0;
        __syncthreads();
        lds[t] += add;
        __syncthreads();
    }
    int j0 = bucket_base[b];
    int p = j0 + lds[t] - c;   // exclusive: row start for node (b,t)
    int run = p;
#pragma unroll
    for (int q = 0; q < Q; ++q) {
        qbase[(b * Q + q) * BUCKET + t] = run;
        run += h[q];
    }
    int node = b * BUCKET + t;
    float s2 = 0.f, s3 = 0.f, s4 = 0.f, sm0 = 0.f, sm1 = 0.f, sc = 0.f;
    if (node < n) {
        pos[node] = p;
        rowend[node] = p + c;
        float d = rsqrtf((float)(c + 1));
        dinv[node] = d;
        float x0 = x[node * 5 + 0], x1 = x[node * 5 + 1], x2 = x[node * 5 + 2];
        float x3 = x[node * 5 + 3], x4 = x[node * 5 + 4];
        float4 o;
        o.x = x0 * d; o.y = x1 * d; o.z = x2 * d; o.w = x3 * d;
        ((float4*)xs)[node * 2] = o;
        xs[node * 8 + 4] = x4 * d;
        s2 = x2; s3 = x3; s4 = x4;
        if (x2 == 1.0f) { sm0 = x0; sm1 = x1; sc = 1.f; }
    }
#pragma unroll
    for (int off = 32; off; off >>= 1) {
        s2 += __shfl_down(s2, off);
        s3 += __shfl_down(s3, off);
        s4 += __shfl_down(s4, off);
        sm0 += __shfl_down(sm0, off);
        sm1 += __shfl_down(sm1, off);
        sc += __shfl_down(sc, off);
    }
    if ((t & 63) == 0) {            // 4 waves -> LDS accumulate (cheap)
        atomicAdd(&gf6[0], s2);
        atomicAdd(&gf6[1], s3);
        atomicAdd(&gf6[2], s4);
        atomicAdd(&gf6[3], sm0);
        atomicAdd(&gf6[4], sm1);
        atomicAdd(&gf6[5], sc);
    }
    __syncthreads();
    if (t < 6) gfpart[b * 8 + t] = gf6[t];
}

// csrC: per-(bucket, slice) scatter into per-node CSR using private cursors
__global__ void k_csrC(const int* __restrict__ records, const int* __restrict__ bucket_base,
                       const int* __restrict__ qbase, int* __restrict__ ssrc) {
    __shared__ int cursor[BUCKET];
    int t = threadIdx.x, b = blockIdx.x, q = blockIdx.y;
    if (t < BUCKET) cursor[t] = qbase[(b * Q + q) * BUCKET + t];
    __syncthreads();
    int j0 = bucket_base[b], j1 = bucket_base[b + 1];
    int qlen = (j1 - j0 + Q - 1) / Q;
    int qs = j0 + q * qlen;
    int qe = min(qs + qlen, j1);
    for (int j = qs + t; j < qe; j += blockDim.x) {
        int rec = records[j];
        int slot = atomicAdd(&cursor[rec >> 17], 1);
        ssrc[slot] = rec & 131071;
    }
}

// 5-dim aggregation: agg5[i,:] = dinv[i] * ( sum_{s in N(i)} xs[s,:] + xs[i,:] )
__global__ void k_agg5(const int* __restrict__ pos, const int* __restrict__ rowend,
                       const int* __restrict__ ssrc, const float* __restrict__ dinv,
                       const float* __restrict__ xs, float* __restrict__ agg5, int n) {
    int i = blockIdx.x * blockDim.x + threadIdx.x;
    if (i >= n) return;
    const float4* xs4 = (const float4*)xs;
    float4 a = xs4[i * 2];            // self term
    float a4 = xs[i * 8 + 4];
    int beg = pos[i], end = rowend[i];
    int j = beg;
    for (; j + 1 < end; j += 2) {
        int s0 = ssrc[j], s1 = ssrc[j + 1];
        float4 v0 = xs4[s0 * 2]; float w0 = xs[s0 * 8 + 4];
        float4 v1 = xs4[s1 * 2]; float w1 = xs[s1 * 8 + 4];
        a.x += v0.x + v1.x; a.y += v0.y + v1.y;
        a.z += v0.z + v1.z; a.w += v0.w + v1.w;
        a4 += w0 + w1;
    }
    for (; j < end; ++j) {
        int s = ssrc[j];
        float4 v = xs4[s * 2];
        a.x += v.x; a.y += v.y; a.z += v.z; a.w += v.w;
        a4 += xs[s * 8 + 4];
    }
    float dd = dinv[i];
    float4 o; o.x = a.x * dd; o.y = a.y * dd; o.z = a.z * dd; o.w = a.w * dd;
    ((float4*)agg5)[i * 2] = o;
    agg5[i * 8 + 4] = a4 * dd;
}

// h1f8[i,f] = fp8_e4m3( dinv[i] * relu( agg5[i,:] @ W1[:,f] + b1[f] ) )
// Row n (one past the end) is written as zeros: the dummy row for padding.
__global__ void k_h1(const float* __restrict__ agg5, const float* __restrict__ W1,
                     const float* __restrict__ b1, const float* __restrict__ dinv,
                     unsigned char* __restrict__ h1f8, int n) {
    int t = blockIdx.x * blockDim.x + threadIdx.x;
    int i = t >> 6, f = t & 63;
    if (i > n) return;
    if (i == n) {                      // zero row for the dummy CSR slot
        h1f8[(size_t)i * 64 + f] = 0;  // fp8 0x00 == 0.0
        return;
    }
    float a0 = agg5[i * 8 + 0], a1 = agg5[i * 8 + 1], a2 = agg5[i * 8 + 2];
    float a3 = agg5[i * 8 + 3], a4 = agg5[i * 8 + 4];
    float v = a0 * W1[f] + a1 * W1[64 + f] + a2 * W1[128 + f]
            + a3 * W1[192 + f] + a4 * W1[256 + f] + b1[f];
    float hv = dinv[i] * fmaxf(v, 0.f);
    int packed = __builtin_amdgcn_cvt_pk_fp8_f32(hv, hv, 0, false);
    h1f8[(size_t)i * 64 + f] = (unsigned char)(packed & 0xFF);
}

// Layer 2 fully fused, 4 nodes per wave interleaved; fp8 rows (64B = 1 line),
// zero-row padding -> unconditional adds; RCOPY-spread accumulation.
// 4096-block grid-stride (~1.5 tasks/wave amortizes per-wave overhead).
__global__ __launch_bounds__(256)
void k_l2fuse(const int* __restrict__ pos, const int* __restrict__ rowend,
              const int* __restrict__ ssrc, const float* __restrict__ dinv,
              const unsigned char* __restrict__ h1f8, const float* __restrict__ W2,
              const float* __restrict__ b2, float* __restrict__ red, int n, int E) {
    __shared__ float red64[64];
    int t = threadIdx.x, f = t & 63;
    if (t < 64) red64[t] = 0.f;
    __syncthreads();
    int w = blockIdx.x * (blockDim.x >> 6) + (t >> 6);
    int nw = gridDim.x * (blockDim.x >> 6);
    float bf = b2[f];
    float psum = 0.f;
    int nt = (n + 3) >> 2;
    for (int task = w; task < nt; task += nw) {
        int i0 = task * 4, i1 = i0 + 1, i2 = i0 + 2, i3 = i0 + 3;
        bool v1 = i1 < n, v2 = i2 < n, v3 = i3 < n;
        int p0 = pos[i0],            e0 = rowend[i0];
        int p1 = v1 ? pos[i1] : 0,   e1 = v1 ? rowend[i1] : 0;
        int p2 = v2 ? pos[i2] : 0,   e2 = v2 ? rowend[i2] : 0;
        int p3 = v3 ? pos[i3] : 0,   e3 = v3 ? rowend[i3] : 0;
        float a0 = __builtin_amdgcn_cvt_f32_fp8(h1f8[(size_t)i0 * 64 + f], 0);
        float a1 = v1 ? __builtin_amdgcn_cvt_f32_fp8(h1f8[(size_t)i1 * 64 + f], 0) : 0.f;
        float a2 = v2 ? __builtin_amdgcn_cvt_f32_fp8(h1f8[(size_t)i2 * 64 + f], 0) : 0.f;
        float a3 = v3 ? __builtin_amdgcn_cvt_f32_fp8(h1f8[(size_t)i3 * 64 + f], 0) : 0.f;
        int len = max(max(e0 - p0, e1 - p1), max(e2 - p2, e3 - p3));
#pragma unroll 2
        for (int m = 0; m < len; ++m) {
            int j0 = p0 + m, j1 = p1 + m, j2 = p2 + m, j3 = p3 + m;
            int s0 = ssrc[j0 < e0 ? j0 : E];   // dummy slot -> zero row
            int s1 = ssrc[j1 < e1 ? j1 : E];
            int s2 = ssrc[j2 < e2 ? j2 : E];
            int s3 = ssrc[j3 < e3 ? j3 : E];
            a0 += __builtin_amdgcn_cvt_f32_fp8(h1f8[(size_t)s0 * 64 + f], 0);
            a1 += __builtin_amdgcn_cvt_f32_fp8(h1f8[(size_t)s1 * 64 + f], 0);
            a2 += __builtin_amdgcn_cvt_f32_fp8(h1f8[(size_t)s2 * 64 + f], 0);
            a3 += __builtin_amdgcn_cvt_f32_fp8(h1f8[(size_t)s3 * 64 + f], 0);
        }
        // conv2: out_k[f] = relu( dinv * sum_kk a_k[kk]*W2[kk,f] + b2[f] )
        float q0 = 0.f, q1 = 0.f, q2 = 0.f, q3 = 0.f;
#pragma unroll 8
        for (int k = 0; k < 64; ++k) {
            float w2v = W2[k * 64 + f];
            q0 += __shfl(a0, k) * w2v;
            q1 += __shfl(a1, k) * w2v;
            q2 += __shfl(a2, k) * w2v;
            q3 += __shfl(a3, k) * w2v;
        }
        psum += fmaxf(q0 * dinv[i0] + bf, 0.f);
        if (v1) psum += fmaxf(q1 * dinv[i1] + bf, 0.f);
        if (v2) psum += fmaxf(q2 * dinv[i2] + bf, 0.f);
        if (v3) psum += fmaxf(q3 * dinv[i3] + bf, 0.f);
    }
    atomicAdd(&red64[f], psum);
    __syncthreads();
    if (t < 64) atomicAdd(&red[(blockIdx.x & (RCOPY - 1)) * 64 + t], red64[t]);
}

// Final head: emb = [mean(h2), gf(6)] (70), MLP 70->32->2, 2+3*sigmoid.
__global__ void k_head(const float* __restrict__ red, const float* __restrict__ gfpart,
                       const float* __restrict__ l1w, const float* __restrict__ l1b,
                       const float* __restrict__ l2w, const float* __restrict__ l2b,
                       float* __restrict__ out, int n, int NBK) {
    __shared__ float emb[70];
    __shared__ float hid[32];
    int t = threadIdx.x;
    if (t < 64) {
        float s = 0.f;
#pragma unroll
        for (int c = 0; c < RCOPY; ++c) s += red[c * 64 + t];
        emb[t] = s / (float)n;
    }
    float g0 = 0.f, g1 = 0.f, g2 = 0.f, g3 = 0.f, g4 = 0.f, g5 = 0.f;
    for (int b = t; b < NBK; b += 64) {
        g0 += gfpart[b * 8 + 0]; g1 += gfpart[b * 8 + 1];
        g2 += gfpart[b * 8 + 2]; g3 += gfpart[b * 8 + 3];
        g4 += gfpart[b * 8 + 4]; g5 += gfpart[b * 8 + 5];
    }
#pragma unroll
    for (int off = 32; off; off >>= 1) {
        g0 += __shfl_down(g0, off); g1 += __shfl_down(g1, off);
        g2 += __shfl_down(g2, off); g3 += __shfl_down(g3, off);
        g4 += __shfl_down(g4, off); g5 += __shfl_down(g5, off);
    }
    if (t == 0) {
        float cnt = g5;
        float safe = fmaxf(cnt, 1.f);
        emb[64] = g0;                       // n_comp
        emb[65] = g1;                       // n_and
        emb[66] = g2;                       // n_or
        emb[67] = g1 + g2;                  // depth
        emb[68] = cnt > 0.f ? g3 / safe : 0.f;   // avg_lambda
        emb[69] = cnt > 0.f ? g4 / safe : 0.f;   // avg_mu
    }
    __syncthreads();
    if (t < 32) {
        float acc = l1b[t];
#pragma unroll
        for (int k = 0; k < 70; ++k) acc += emb[k] * l1w[k * 32 + t];
        hid[t] = fmaxf(acc, 0.f);
    }
    __syncthreads();
    if (t < 2) {
        float acc = l2b[t];
#pragma unroll
        for (int j = 0; j < 32; ++j) acc += hid[j] * l2w[j * 2 + t];
        out[t] = 2.0f + 3.0f / (1.0f + expf(-acc));
    }
}

extern "C" void kernel_launch(void* const* d_in, const int* in_sizes, int n_in,
                              void* d_out, int out_size, void* d_ws, size_t ws_size,
                              hipStream_t stream) {
    const float* x   = (const float*)d_in[0];
    const int*   ei  = (const int*)d_in[1];
    const float* w1  = (const float*)d_in[2];
    const float* b1  = (const float*)d_in[3];
    const float* w2  = (const float*)d_in[4];
    const float* b2  = (const float*)d_in[5];
    const float* l1w = (const float*)d_in[6];
    const float* l1b = (const float*)d_in[7];
    const float* l2w = (const float*)d_in[8];
    const float* l2b = (const float*)d_in[9];

    const int n = in_sizes[0] / 5;
    const int E = in_sizes[1] / 2;
    const int* src = ei;
    const int* dst = ei + E;

    const int NBK = (n + BUCKET - 1) / BUCKET;   // 391 buckets
    const int NCH = NCHV;                         // 2048 edge chunks
    const int chunk = (E + NCH - 1) / NCH;

    size_t nf = (size_t)(n + 1) * 64;             // +1: zero row at index n
    unsigned char* h1f8 = (unsigned char*)d_ws;       // (N+1) x 64 fp8
    float* xs          = (float*)(h1f8 + ((nf + 255) & ~(size_t)255));
    float* agg5        = xs + (size_t)n * 8;          // N x 8 (padded)
    float* dinv        = agg5 + (size_t)n * 8;
    float* red         = dinv + n;                    // RCOPY*64 floats
    float* gfpart      = red + RCOPY * 64;            // NBK*8 floats
    int*   pos         = (int*)(gfpart + (MAXB * 8));
    int*   rowend      = pos + n;
    int*   btot        = rowend + n;                  // MAXB ints
    int*   bucket_base = btot + MAXB;                 // NBK+1
    int*   qhist       = bucket_base + (MAXB + 8);    // NBK*Q*256
    int*   qbase       = qhist + NBK * Q * BUCKET;    // NBK*Q*256
    int*   gcounts     = qbase + NBK * Q * BUCKET;    // NCH*NBK
    int*   records     = gcounts + NCH * NBK;         // E ints
    int*   ssrc        = records + E;                 // E+1 ints (slot E = dummy)

    k_hist<<<NCH, 512, 0, stream>>>(dst, E, chunk, gcounts, NBK);
    k_colsum<<<NBK, 256, 0, stream>>>(gcounts, btot, NBK, NCH);
    k_scanA<<<1, MAXB, 0, stream>>>(btot, bucket_base, red, ssrc, E, n, NBK);
    k_scanB<<<NBK, 512, 0, stream>>>(gcounts, bucket_base, NBK, NCH);
    k_bucketize<<<NCH, 512, 0, stream>>>(src, dst, E, chunk, gcounts, records, NBK);

    dim3 qgrid(NBK, Q);
    k_csrA<<<qgrid, 512, 0, stream>>>(records, bucket_base, qhist);
    k_csrB<<<NBK, BUCKET, 0, stream>>>(qhist, bucket_base, x, qbase, pos, rowend,
                                       dinv, xs, gfpart, n);
    k_csrC<<<qgrid, 512, 0, stream>>>(records, bucket_base, qbase, ssrc);

    k_agg5<<<(n + 255) / 256, 256, 0, stream>>>(pos, rowend, ssrc, dinv, xs, agg5, n);
    k_h1<<<(int)((nf + 255) / 256), 256, 0, stream>>>(agg5, w1, b1, dinv, h1f8, n);

    k_l2fuse<<<4096, 256, 0, stream>>>(pos, rowend, ssrc, dinv, h1f8, w2, b2, red, n, E);

    k_head<<<1, 64, 0, stream>>>(red, gfpart, l1w, l1b, l2w, l2b, (float*)d_out, n, NBK);
}